// Round 1
// baseline (608.192 us; speedup 1.0000x reference)
//
#include <hip/hip_runtime.h>
#include <math.h>

// Problem constants (fixed by setup_inputs): B=64, Q=1024, N=2048, C=2048, P=512, WIN=256
#define Bb  64
#define Qq  1024
#define Nn  2048
#define Cc  2048
#define Pp  512
#define WIN 256

// Key reduction: softmax over the SINGLETON axis of (B,W,1) == 1.0 for finite
// scores, and the window is guaranteed in-bounds (no -inf/NaN path), so the
// whole w_a / proj / a_t branch is dead. Output is just:
//   s_t[b,q] = sum_k exp(-2*((p-128+k - p_t)/128)^2) * q_i[b, q, p-128+k]
// with p_t = 2047*sigmoid(sum_p v_p[p]*tanh(dot(c_t[b], w_p[p]))), p=rint(p_t).

// ---------------- k1a: partial GEMV  d[b,p] = dot(c_t[b,:], w_p[p,:]) -------
// grid 512 = 64 p-chunks (8 rows) x 8 kcb; block 256 = 4 waves, wave kc = kcb*4+w
// lane = batch (64 lanes == 64 batches). w_p addresses are wave-uniform ->
// scalar loads; c_t is a per-lane strided read (L1-resident 16KB/wave window).
__global__ __launch_bounds__(256) void k1a_gemv(const float* __restrict__ c_t,
                                                const float* __restrict__ w_p,
                                                float* __restrict__ partial) {
  const int pc   = blockIdx.x >> 3;     // 0..63
  const int kcb  = blockIdx.x & 7;      // 0..7
  const int w    = threadIdx.x >> 6;    // 0..3
  const int lane = threadIdx.x & 63;    // batch index
  const int kc   = __builtin_amdgcn_readfirstlane(kcb * 4 + w); // 0..31 (uniform)
  const int c0   = kc * 64;
  const int p0   = pc * 8;
  const float* cb = c_t + lane * Cc + c0;
  float acc[8] = {0.f, 0.f, 0.f, 0.f, 0.f, 0.f, 0.f, 0.f};
#pragma unroll
  for (int cq = 0; cq < 16; ++cq) {
    const float4 cv = *reinterpret_cast<const float4*>(cb + cq * 4);
#pragma unroll
    for (int i = 0; i < 8; ++i) {
      const float4 wv =
          *reinterpret_cast<const float4*>(w_p + (p0 + i) * Cc + c0 + cq * 4);
      acc[i] = fmaf(cv.x, wv.x, acc[i]);
      acc[i] = fmaf(cv.y, wv.y, acc[i]);
      acc[i] = fmaf(cv.z, wv.z, acc[i]);
      acc[i] = fmaf(cv.w, wv.w, acc[i]);
    }
  }
  // combine the block's 4 waves (4 consecutive kc) -> one kcb partial
  __shared__ float red[4][8][64];
#pragma unroll
  for (int i = 0; i < 8; ++i) red[w][i][lane] = acc[i];
  __syncthreads();
#pragma unroll
  for (int j = 0; j < 2; ++j) {
    const int idx = threadIdx.x + 256 * j;  // 0..511 = 8p x 64b
    const int pi = idx >> 6, bb = idx & 63;
    const float s =
        red[0][pi][bb] + red[1][pi][bb] + red[2][pi][bb] + red[3][pi][bb];
    partial[(size_t)((bb << 9) + p0 + pi) * 8 + kcb] = s;
  }
}

// ---------------- k1b: finish p_t, emit gaussian weights + base -------------
__global__ __launch_bounds__(256) void k1b_finish(const float* __restrict__ partial,
                                                  const float* __restrict__ v_p,
                                                  float* __restrict__ g,
                                                  int* __restrict__ basei) {
  const int b = blockIdx.x;
  const int t = threadIdx.x;
  float zs = 0.f;
#pragma unroll
  for (int j = 0; j < 2; ++j) {
    const int p = t + 256 * j;
    const float4* pp =
        reinterpret_cast<const float4*>(partial + (size_t)(b * Pp + p) * 8);
    const float4 a = pp[0], c = pp[1];
    const float d = ((a.x + a.y) + (a.z + a.w)) + ((c.x + c.y) + (c.z + c.w));
    zs += tanhf(d) * v_p[p];
  }
  __shared__ float red[256];
  red[t] = zs;
  __syncthreads();
  for (int s = 128; s > 0; s >>= 1) {
    if (t < s) red[t] += red[t + s];
    __syncthreads();
  }
  __shared__ float spt;
  __shared__ int sbase;
  if (t == 0) {
    const float z = red[0];
    const float loc = 1.f / (1.f + expf(-z));
    const float pt = loc * 2047.f;           // loc * (size-2), size = N+1
    const int p = (int)rintf(pt);            // round-half-even == jnp.round
    const int base = p - 128;                // n = base + k, k in [0,256)
    int bc = base < 0 ? 0 : base;            // safety clamp (never hit in-bounds)
    if (bc > Nn - WIN) bc = Nn - WIN;
    spt = pt;
    sbase = base;
    basei[b] = bc;
  }
  __syncthreads();
  const float pt = spt;
  const float d = ((float)(sbase + t) - pt) * (1.f / 128.f);
  g[(b << 8) + t] = expf(-2.f * d * d);
}

// ---------------- k2: gathered weighted sum (memory-bound main kernel) ------
// one wave per 2 rows; lane l covers window offsets l+64j, fully coalesced.
__global__ __launch_bounds__(256) void k2_gather(const float* __restrict__ q,
                                                 const float* __restrict__ g,
                                                 const int* __restrict__ basei,
                                                 float* __restrict__ out) {
  const int wave = (blockIdx.x * 256 + threadIdx.x) >> 6;  // 0..32767
  const int lane = threadIdx.x & 63;
  const int r0 = wave << 1;       // 2 rows per wave
  const int b = r0 >> 10;
  const int base = basei[b];
  const float* gb = g + (b << 8);
  const float g0 = gb[lane], g1 = gb[lane + 64];
  const float g2 = gb[lane + 128], g3 = gb[lane + 192];
#pragma unroll
  for (int rr = 0; rr < 2; ++rr) {
    const int r = r0 + rr;
    const float* row = q + ((size_t)r << 11) + base;
    float a = g0 * row[lane];
    a = fmaf(g1, row[lane + 64], a);
    a = fmaf(g2, row[lane + 128], a);
    a = fmaf(g3, row[lane + 192], a);
#pragma unroll
    for (int off = 32; off > 0; off >>= 1) a += __shfl_xor(a, off, 64);
    if (lane == 0) out[r] = a;
  }
}

extern "C" void kernel_launch(void* const* d_in, const int* in_sizes, int n_in,
                              void* d_out, int out_size, void* d_ws, size_t ws_size,
                              hipStream_t stream) {
  const float* q_i = (const float*)d_in[0];
  const float* c_t = (const float*)d_in[1];
  // d_in[2] = w_a : dead code (softmax over singleton axis == 1)
  const float* w_p = (const float*)d_in[3];
  const float* v_p = (const float*)d_in[4];
  // d_in[5] = window (==256, baked into WIN)
  float* out = (float*)d_out;

  // ws layout: partial [64][512][8] f32 (1MB) | g [64][256] f32 | base [64] i32
  float* partial = (float*)d_ws;
  float* g = partial + (size_t)Bb * Pp * 8;
  int* basei = (int*)(g + Bb * 256);

  k1a_gemv<<<512, 256, 0, stream>>>(c_t, w_p, partial);
  k1b_finish<<<Bb, 256, 0, stream>>>(partial, v_p, g, basei);
  k2_gather<<<8192, 256, 0, stream>>>(q_i, g, basei, out);
}